// Round 4
// baseline (645.156 us; speedup 1.0000x reference)
//
#include <hip/hip_runtime.h>
#include <stdint.h>

#define B_ 32
#define T_ 4096
#define D_ 256
#define S_ 8
#define ITERS_ 3
#define SCALE_ 0.0625f   // 256^-0.5
#define EPS_ 1e-8f
#define NCH 16
#define CHUNK (T_/NCH)   // 256

typedef short short8 __attribute__((ext_vector_type(8)));
typedef float f32x4 __attribute__((ext_vector_type(4)));

__device__ __forceinline__ uint32_t f2bf1(float x){
  union { float f; uint32_t u; } c; c.f = x;
  return (c.u + 0x7fffu + ((c.u >> 16) & 1u)) >> 16;
}
__device__ __forceinline__ uint32_t pack2bf(float a, float b){
  return f2bf1(a) | (f2bf1(b) << 16);
}
__device__ __forceinline__ uint32_t cvtpk2bf(float a, float b){
  uint32_t r;
  asm("v_cvt_pk_bf16_f32 %0, %1, %2" : "=v"(r) : "v"(a), "v"(b));
  return r;
}
__device__ __forceinline__ float bflo(uint32_t u){ union{uint32_t u;float f;} c; c.u = u << 16; return c.f; }
__device__ __forceinline__ float bfhi(uint32_t u){ union{uint32_t u;float f;} c; c.u = u & 0xffff0000u; return c.f; }

// ---------------- mega prep: weight transforms + slot init, one launch ----------------
// block ranges: [0,512) wconv | [512,768) wq | [768,1792) bcat | [1792] bc
//               [1793,2817) w1t | [2817,3073) w2t | [3073,3329) init
__global__ __launch_bounds__(256) void k_prep(const float* __restrict__ Wk, const float* __restrict__ Wv,
                                              const float* __restrict__ Wq,
                                              const float* __restrict__ wih, const float* __restrict__ whh,
                                              const float* __restrict__ bih, const float* __restrict__ bhh,
                                              const float* __restrict__ w1, const float* __restrict__ w2,
                                              const float* __restrict__ mu, const float* __restrict__ ls,
                                              const float* __restrict__ noise,
                                              uint16_t* __restrict__ Wt, uint16_t* __restrict__ Wqt,
                                              uint16_t* __restrict__ Bcat, float* __restrict__ bc,
                                              uint16_t* __restrict__ w1t, uint16_t* __restrict__ w2t,
                                              float* __restrict__ slots){
  int g = blockIdx.x, tid = threadIdx.x;
  if (g < 512){                         // Wt[n][k] = (n<256?Wk:Wv) col n
    int n = g, k = tid;
    float v = (n < 256) ? Wk[k*256 + n] : Wv[k*256 + (n - 256)];
    Wt[n*256 + k] = (uint16_t)f2bf1(v);
  } else if (g < 768){                  // Wqt = Wq^T * SCALE
    int n = g - 512, k = tid;
    Wqt[n*256 + k] = (uint16_t)f2bf1(Wq[k*256 + n] * SCALE_);
  } else if (g < 1792){                 // Bcat [1024n][512k]
    int n = g - 768;
    #pragma unroll
    for (int j = 0; j < 2; ++j){
      int k = j*256 + tid;
      float v;
      if (n < 768) v = (k < 256) ? wih[k*768 + n] : whh[(k-256)*768 + n];
      else         v = (k < 256) ? 0.f            : whh[(k-256)*768 + 512 + (n-768)];
      Bcat[(size_t)n*512 + k] = (uint16_t)f2bf1(v);
    }
  } else if (g < 1793){                 // bc [1024]
    #pragma unroll
    for (int j = 0; j < 4; ++j){
      int i = j*256 + tid;
      float v;
      if (i < 512) v = bih[i] + bhh[i];
      else if (i < 768) v = bih[i];
      else v = bhh[i - 256];
      bc[i] = v;
    }
  } else if (g < 2817){                 // w1t [1024n][256k]
    int n = g - 1793, k = tid;
    w1t[(size_t)n*256 + k] = (uint16_t)f2bf1(w1[(size_t)k*1024 + n]);
  } else if (g < 3073){                 // w2t [256n][1024k]
    int n = g - 2817;
    #pragma unroll
    for (int j = 0; j < 4; ++j){
      int k = j*256 + tid;
      w2t[(size_t)n*1024 + k] = (uint16_t)f2bf1(w2[(size_t)k*256 + n]);
    }
  } else {                              // slots init
    int i = (g - 3073)*256 + tid;
    int d = i & 255;
    slots[i] = mu[d] + __expf(ls[d]) * noise[i];
  }
}

// ---------------- projection GEMM: [131072,256]x[256,512] -> K,V bf16 ----------------
#define PPITCH 40
__global__ __launch_bounds__(256) void k_proj(const float* __restrict__ X,
                                              const uint16_t* __restrict__ Wt,
                                              uint16_t* __restrict__ Kp,
                                              uint16_t* __restrict__ Vp){
  __shared__ __align__(16) uint16_t As[128*PPITCH];
  __shared__ __align__(16) uint16_t Bs[128*PPITCH];
  __shared__ __align__(16) uint16_t Cs[128*128];
  int bid = blockIdx.x;
  int x = bid & 7, j = bid >> 3;
  int tau = 512*x + j;
  int mt = tau >> 2;
  int nt = tau & 3;
  int m0 = mt * 128;
  int n0 = nt * 128;
  int tid = threadIdx.x;
  int lane = tid & 63, wid = tid >> 6;
  int wm = wid >> 1, wn = wid & 1;
  int rsel = lane & 15, g = lane >> 4;

  f32x4 acc[4][4];
  for (int a = 0; a < 4; ++a)
    for (int b = 0; b < 4; ++b)
      acc[a][b] = (f32x4){0.f,0.f,0.f,0.f};

  for (int ks = 0; ks < 8; ++ks){
    int k0 = ks*32;
    #pragma unroll
    for (int i = 0; i < 2; ++i){
      int task = i*256 + tid;
      int row = task >> 2, seg = task & 3;
      const float* gp = X + (size_t)(m0 + row)*256 + k0 + seg*8;
      float4 a = *(const float4*)gp;
      float4 b = *(const float4*)(gp + 4);
      uint4 w;
      w.x = cvtpk2bf(a.x, a.y); w.y = cvtpk2bf(a.z, a.w);
      w.z = cvtpk2bf(b.x, b.y); w.w = cvtpk2bf(b.z, b.w);
      *(uint4*)&As[row*PPITCH + seg*8] = w;
    }
    #pragma unroll
    for (int i = 0; i < 2; ++i){
      int task = i*256 + tid;
      int row = task >> 2, seg = task & 3;
      uint4 v = *(const uint4*)(Wt + (size_t)(n0 + row)*256 + k0 + seg*8);
      *(uint4*)&Bs[row*PPITCH + seg*8] = v;
    }
    __syncthreads();
    short8 af[4], bfr[4];
    #pragma unroll
    for (int t = 0; t < 4; ++t)
      af[t] = *(const short8*)&As[(wm*64 + t*16 + rsel)*PPITCH + g*8];
    #pragma unroll
    for (int t = 0; t < 4; ++t)
      bfr[t] = *(const short8*)&Bs[(wn*64 + t*16 + rsel)*PPITCH + g*8];
    #pragma unroll
    for (int a = 0; a < 4; ++a)
      #pragma unroll
      for (int b = 0; b < 4; ++b)
        acc[a][b] = __builtin_amdgcn_mfma_f32_16x16x32_bf16(af[a], bfr[b], acc[a][b], 0, 0, 0);
    __syncthreads();
  }
  #pragma unroll
  for (int a = 0; a < 4; ++a)
    #pragma unroll
    for (int b = 0; b < 4; ++b)
      #pragma unroll
      for (int r = 0; r < 4; ++r){
        int mrow = wm*64 + a*16 + g*4 + r;
        int ncol = wn*64 + b*16 + rsel;
        Cs[mrow*128 + ncol] = (uint16_t)f2bf1(acc[a][b][r]);
      }
  __syncthreads();
  uint16_t* outp = (n0 < 256) ? Kp : Vp;
  int nbase = n0 & 255;
  #pragma unroll
  for (int i = 0; i < 4; ++i){
    int task = i*256 + tid;
    int row = task >> 3, seg = task & 7;
    uint4 v = *(uint4*)&Cs[row*128 + seg*16];
    *(uint4*)&outp[(size_t)(m0 + row)*256 + nbase + seg*16] = v;
  }
}

// ---------------- fused LN(slots)+Wq GEMM -> qbf (scale folded in Wqt) ----------------
__global__ __launch_bounds__(256) void k_qln(const float* __restrict__ slots,
                                             const uint16_t* __restrict__ Wqt,
                                             const float* __restrict__ ng,
                                             const float* __restrict__ nb,
                                             uint16_t* __restrict__ qbf){
  __shared__ __align__(16) uint16_t snl[16*264];
  int m0 = blockIdx.x * 16;
  int tid = threadIdx.x;
  int r = tid >> 4, cs = (tid & 15) * 16;
  // LN: each thread owns 16 elems of row r
  float xv[16];
  {
    const float* sp = slots + (size_t)(m0 + r)*256 + cs;
    #pragma unroll
    for (int i = 0; i < 4; ++i){
      float4 v = *(const float4*)(sp + i*4);
      xv[i*4+0]=v.x; xv[i*4+1]=v.y; xv[i*4+2]=v.z; xv[i*4+3]=v.w;
    }
  }
  float s1 = 0.f, s2 = 0.f;
  #pragma unroll
  for (int i = 0; i < 16; ++i){ s1 += xv[i]; s2 += xv[i]*xv[i]; }
  #pragma unroll
  for (int m = 1; m < 16; m <<= 1){ s1 += __shfl_xor(s1, m, 64); s2 += __shfl_xor(s2, m, 64); }
  float mu = s1 * (1.f/256.f);
  float ms = s2 * (1.f/256.f);
  float rstd = rsqrtf(ms - mu*mu + 1e-5f);
  {
    uint32_t pk[8];
    #pragma unroll
    for (int i = 0; i < 8; ++i){
      float a = (xv[2*i]   - mu)*rstd*ng[cs+2*i]   + nb[cs+2*i];
      float b = (xv[2*i+1] - mu)*rstd*ng[cs+2*i+1] + nb[cs+2*i+1];
      pk[i] = pack2bf(a, b);
    }
    uint4* dst = (uint4*)&snl[r*264 + cs];
    dst[0] = (uint4){pk[0],pk[1],pk[2],pk[3]};
    dst[1] = (uint4){pk[4],pk[5],pk[6],pk[7]};
  }
  __syncthreads();
  int lane = tid & 63, w = tid >> 6;
  int rsel = lane & 15, g = lane >> 4;
  short8 aq[8];
  #pragma unroll
  for (int kk = 0; kk < 8; ++kk)
    aq[kk] = *(const short8*)((const char*)snl + rsel*528 + kk*64 + g*16);
  int n0w = w*64;
  #pragma unroll
  for (int nt = 0; nt < 4; ++nt){
    f32x4 acc = (f32x4){0.f,0.f,0.f,0.f};
    #pragma unroll
    for (int kk = 0; kk < 8; ++kk){
      short8 bfr = *(const short8*)&Wqt[(size_t)(n0w + nt*16 + rsel)*256 + kk*32 + g*8];
      acc = __builtin_amdgcn_mfma_f32_16x16x32_bf16(aq[kk], bfr, acc, 0, 0, 0);
    }
    #pragma unroll
    for (int r4 = 0; r4 < 4; ++r4){
      int row = g*4 + r4;
      qbf[(size_t)(m0 + row)*256 + n0w + nt*16 + rsel] = (uint16_t)f2bf1(acc[r4]);
    }
  }
}

// ---------------- G GEMM: G[256,1024] = Acat[256,512] x Bcat[1024,512]^T ----------------
#define GPIT 40
__global__ __launch_bounds__(256) void k_gemmG(const uint16_t* __restrict__ A,
                                               const uint16_t* __restrict__ Bm,
                                               float* __restrict__ Cf){
  __shared__ __align__(16) uint16_t As[64*GPIT];
  __shared__ __align__(16) uint16_t Bs[64*GPIT];
  const int N = 1024, K = 512;
  int m0 = blockIdx.y * 64, n0 = blockIdx.x * 64;
  int tid = threadIdx.x, lane = tid & 63, wid = tid >> 6;
  int wm = wid >> 1, wn = wid & 1;
  int rsel = lane & 15, g = lane >> 4;
  f32x4 acc[2][2];
  #pragma unroll
  for (int a = 0; a < 2; ++a)
    #pragma unroll
    for (int b = 0; b < 2; ++b)
      acc[a][b] = (f32x4){0.f,0.f,0.f,0.f};
  int row_s = tid >> 2, seg = tid & 3;
  for (int k0 = 0; k0 < K; k0 += 32){
    *(uint4*)&As[row_s*GPIT + seg*8] = *(const uint4*)(A  + (size_t)(m0+row_s)*K + k0 + seg*8);
    *(uint4*)&Bs[row_s*GPIT + seg*8] = *(const uint4*)(Bm + (size_t)(n0+row_s)*K + k0 + seg*8);
    __syncthreads();
    short8 af[2], bfr[2];
    #pragma unroll
    for (int t = 0; t < 2; ++t)
      af[t]  = *(const short8*)&As[(wm*32 + t*16 + rsel)*GPIT + g*8];
    #pragma unroll
    for (int t = 0; t < 2; ++t)
      bfr[t] = *(const short8*)&Bs[(wn*32 + t*16 + rsel)*GPIT + g*8];
    #pragma unroll
    for (int a = 0; a < 2; ++a)
      #pragma unroll
      for (int b = 0; b < 2; ++b)
        acc[a][b] = __builtin_amdgcn_mfma_f32_16x16x32_bf16(af[a], bfr[b], acc[a][b], 0, 0, 0);
    __syncthreads();
  }
  #pragma unroll
  for (int a = 0; a < 2; ++a)
    #pragma unroll
    for (int b = 0; b < 2; ++b)
      #pragma unroll
      for (int r = 0; r < 4; ++r){
        int mrow = m0 + wm*32 + a*16 + g*4 + r;
        int ncol = n0 + wn*32 + b*16 + rsel;
        Cf[(size_t)mrow*N + ncol] = acc[a][b][r];
      }
}

// ---------------- reduce attn partials -> Acat bf16 [256][512] = [u | h] ----------------
__global__ __launch_bounds__(256) void k_gru_pre(const float* __restrict__ upd_part,
                                                 const float* __restrict__ sum_part,
                                                 const float* __restrict__ slots,
                                                 uint16_t* __restrict__ Acat){
  int row = blockIdx.x;
  int b = row >> 3, s = row & 7;
  int d = threadIdx.x;
  float sum = 0.f;
  #pragma unroll
  for (int ch = 0; ch < 16; ++ch) sum += sum_part[(size_t)(b*16 + ch)*8 + s];
  float acc = 0.f;
  #pragma unroll
  for (int ch = 0; ch < 16; ++ch) acc += upd_part[(size_t)(b*16 + ch)*2048 + s*256 + d];
  Acat[(size_t)row*512 + d]       = (uint16_t)f2bf1(acc / sum);
  Acat[(size_t)row*512 + 256 + d] = (uint16_t)f2bf1(slots[row*256 + d]);
}

// ---------------- GRU combine + LN -> s2f fp32, snb bf16 ----------------
__global__ __launch_bounds__(256) void k_combine(const float* __restrict__ G,
                                                 const float* __restrict__ bc,
                                                 const float* __restrict__ slots,
                                                 const float* __restrict__ mng,
                                                 const float* __restrict__ mnb,
                                                 float* __restrict__ s2f,
                                                 uint16_t* __restrict__ snb){
  __shared__ float red[8];
  int row = blockIdx.x, c = threadIdx.x;
  int lane = c & 63, wid = c >> 6;
  const float* Gr = G + (size_t)row*1024;
  float r  = 1.f / (1.f + __expf(-(Gr[c]       + bc[c])));
  float z  = 1.f / (1.f + __expf(-(Gr[256 + c] + bc[256 + c])));
  float Gn = Gr[512 + c], Gh = Gr[768 + c];
  float nn = tanhf((Gn - Gh + bc[512 + c]) + r*(Gh + bc[768 + c]));
  float hv = slots[row*256 + c];
  float s2 = (1.f - z)*nn + z*hv;
  s2f[row*256 + c] = s2;
  float p1 = s2, p2 = s2*s2;
  #pragma unroll
  for (int d = 32; d; d >>= 1){ p1 += __shfl_down(p1, d, 64); p2 += __shfl_down(p2, d, 64); }
  if (lane == 0){ red[wid] = p1; red[4 + wid] = p2; }
  __syncthreads();
  float mu = (red[0]+red[1]+red[2]+red[3]) * (1.f/256.f);
  float ms = (red[4]+red[5]+red[6]+red[7]) * (1.f/256.f);
  float rstd = rsqrtf(ms - mu*mu + 1e-5f);
  snb[row*256 + c] = (uint16_t)f2bf1((s2 - mu)*rstd*mng[c] + mnb[c]);
}

// ---------------- fused MLP: h=relu(snb@w1t^T+b1) in LDS; slots = s2f + h@w2t^T + b2 ----------------
#define HPIT 1048   // u16 pitch (2096 B: 16B-aligned, bank-friendly)
__global__ __launch_bounds__(256) void k_mlp(const uint16_t* __restrict__ snb,
                                             const uint16_t* __restrict__ w1t,
                                             const float* __restrict__ b1,
                                             const uint16_t* __restrict__ w2t,
                                             const float* __restrict__ b2,
                                             const float* __restrict__ s2f,
                                             float* __restrict__ slots){
  __shared__ __align__(16) uint16_t h1s[16*HPIT];
  int m0 = blockIdx.x * 16;
  int tid = threadIdx.x, lane = tid & 63, w = tid >> 6;
  int rsel = lane & 15, g = lane >> 4;
  // A-frags: snb rows m0..m0+15
  short8 aq[8];
  #pragma unroll
  for (int kk = 0; kk < 8; ++kk)
    aq[kk] = *(const short8*)&snb[(size_t)(m0 + rsel)*256 + kk*32 + g*8];
  // phase 1: hidden, wave w owns n in [w*256, w*256+256)
  #pragma unroll
  for (int nt = 0; nt < 16; ++nt){
    int ncol = w*256 + nt*16 + rsel;
    f32x4 acc = (f32x4){0.f,0.f,0.f,0.f};
    #pragma unroll
    for (int kk = 0; kk < 8; ++kk){
      short8 bfr = *(const short8*)&w1t[(size_t)ncol*256 + kk*32 + g*8];
      acc = __builtin_amdgcn_mfma_f32_16x16x32_bf16(aq[kk], bfr, acc, 0, 0, 0);
    }
    float bv = b1[ncol];
    #pragma unroll
    for (int r4 = 0; r4 < 4; ++r4){
      int row = g*4 + r4;
      h1s[row*HPIT + ncol] = (uint16_t)f2bf1(fmaxf(acc[r4] + bv, 0.f));
    }
  }
  __syncthreads();
  // phase 2: out, wave w owns n in [w*64, +64)
  f32x4 acc2[4];
  #pragma unroll
  for (int nt = 0; nt < 4; ++nt) acc2[nt] = (f32x4){0.f,0.f,0.f,0.f};
  for (int kk = 0; kk < 32; ++kk){
    short8 aq2 = *(const short8*)((const char*)h1s + rsel*2096 + kk*64 + g*16);
    #pragma unroll
    for (int nt = 0; nt < 4; ++nt){
      short8 bfr = *(const short8*)&w2t[(size_t)(w*64 + nt*16 + rsel)*1024 + kk*32 + g*8];
      acc2[nt] = __builtin_amdgcn_mfma_f32_16x16x32_bf16(aq2, bfr, acc2[nt], 0, 0, 0);
    }
  }
  #pragma unroll
  for (int nt = 0; nt < 4; ++nt){
    int ncol = w*64 + nt*16 + rsel;
    float bv = b2[ncol];
    #pragma unroll
    for (int r4 = 0; r4 < 4; ++r4){
      int row = m0 + g*4 + r4;
      slots[(size_t)row*256 + ncol] = s2f[(size_t)row*256 + ncol] + acc2[nt][r4] + bv;
    }
  }
}

// ---------------- per-iter: fused dots->softmax(S)->unnorm PV accumulate ----------------
__global__ __launch_bounds__(256) void k_attn(const uint16_t* __restrict__ qbf,
                                              const uint16_t* __restrict__ Kp,
                                              const uint16_t* __restrict__ Vp,
                                              float* __restrict__ upd_part,
                                              float* __restrict__ sum_part){
  __shared__ __align__(16) uint16_t qs[16*264];
  __shared__ __align__(16) uint16_t Ks[64*264];
  __shared__ __align__(16) uint32_t attp[64*4];
  __shared__ float red[8*256];
  __shared__ float ssum[8];
  int bid = blockIdx.x;
  int b = bid >> 4, ch = bid & 15;
  int tid = threadIdx.x, lane = tid & 63, wid = tid >> 6;
  {
    const uint32_t* qg = (const uint32_t*)(qbf + (size_t)b*2048);
    uint32_t* qd = (uint32_t*)qs;
    #pragma unroll
    for (int i = 0; i < 4; ++i){
      int idx = i*256 + tid;
      int s = idx >> 7, c = idx & 127;
      qd[s*132 + c] = qg[idx];
    }
    #pragma unroll
    for (int i = 0; i < 5; ++i){
      int idx = i*256 + tid;
      if (idx < 1056) qd[8*132 + idx] = 0u;
    }
  }
  if (tid < 8) ssum[tid] = 0.f;
  __syncthreads();
  short8 aq[8];
  {
    int rs = lane & 15, g = lane >> 4;
    const char* qb = (const char*)qs;
    #pragma unroll
    for (int kk = 0; kk < 8; ++kk)
      aq[kk] = *(const short8*)(qb + rs*528 + kk*64 + g*16);
  }
  float upd[8][4];
  #pragma unroll
  for (int s = 0; s < 8; ++s){ upd[s][0]=0.f; upd[s][1]=0.f; upd[s][2]=0.f; upd[s][3]=0.f; }
  float sp[4] = {0.f,0.f,0.f,0.f};
  int dd = lane * 4;
  int tq = wid;

  for (int st = 0; st < 4; ++st){
    int t0 = ch*CHUNK + st*64;
    {
      const char* kg = (const char*)Kp + ((size_t)(b*T_ + t0) << 9);
      char* kd = (char*)Ks;
      #pragma unroll
      for (int i = 0; i < 8; ++i){
        int task = i*256 + tid;
        int row = task >> 5, seg = task & 31;
        uint4 v = *(const uint4*)(kg + (row << 9) + (seg << 4));
        *(uint4*)(kd + row*528 + seg*16) = v;
      }
    }
    __syncthreads();
    f32x4 dot = (f32x4){0.f,0.f,0.f,0.f};
    int col = lane & 15, g = lane >> 4;
    {
      const char* kb = (const char*)Ks + (wid*16 + col)*528 + g*16;
      #pragma unroll
      for (int kk = 0; kk < 8; ++kk){
        short8 bf = *(const short8*)(kb + kk*64);
        dot = __builtin_amdgcn_mfma_f32_16x16x32_bf16(aq[kk], bf, dot, 0, 0, 0);
      }
    }
    float x0 = dot[0], x1 = dot[1], x2 = dot[2], x3 = dot[3];
    float y0 = __shfl_xor(x0, 16, 64), y1 = __shfl_xor(x1, 16, 64);
    float y2 = __shfl_xor(x2, 16, 64), y3 = __shfl_xor(x3, 16, 64);
    float m = fmaxf(fmaxf(fmaxf(x0,x1), fmaxf(x2,x3)), fmaxf(fmaxf(y0,y1), fmaxf(y2,y3)));
    float e0 = __expf(x0-m), e1 = __expf(x1-m), e2 = __expf(x2-m), e3 = __expf(x3-m);
    float f0 = __expf(y0-m), f1 = __expf(y1-m), f2 = __expf(y2-m), f3 = __expf(y3-m);
    float inv = 1.f / (e0+e1+e2+e3+f0+f1+f2+f3);
    float p0 = e0*inv + EPS_, p1 = e1*inv + EPS_, p2 = e2*inv + EPS_, p3 = e3*inv + EPS_;
    if (g < 2){
      sp[0] += p0; sp[1] += p1; sp[2] += p2; sp[3] += p3;
      int t = wid*16 + col;
      attp[t*4 + g*2 + 0] = pack2bf(p0, p1);
      attp[t*4 + g*2 + 1] = pack2bf(p2, p3);
    }
    __syncthreads();
    {
      const char* vg = (const char*)Vp + ((size_t)(b*T_ + t0) << 9) + (size_t)dd*2;
      #pragma unroll
      for (int tt = 0; tt < 16; ++tt){
        int tl = tq*16 + tt;
        uint2 vv = *(const uint2*)(vg + ((size_t)tl << 9));
        uint4 aa = *(const uint4*)&attp[tl*4];
        float v0 = bflo(vv.x), v1 = bfhi(vv.x), v2 = bflo(vv.y), v3 = bfhi(vv.y);
        float av[8];
        av[0] = bflo(aa.x); av[1] = bfhi(aa.x); av[2] = bflo(aa.y); av[3] = bfhi(aa.y);
        av[4] = bflo(aa.z); av[5] = bfhi(aa.z); av[6] = bflo(aa.w); av[7] = bfhi(aa.w);
        #pragma unroll
        for (int s = 0; s < 8; ++s){
          upd[s][0] = fmaf(av[s], v0, upd[s][0]);
          upd[s][1] = fmaf(av[s], v1, upd[s][1]);
          upd[s][2] = fmaf(av[s], v2, upd[s][2]);
          upd[s][3] = fmaf(av[s], v3, upd[s][3]);
        }
      }
    }
    __syncthreads();
  }
  for (int ph = 0; ph < 4; ++ph){
    if (tq == ph){
      #pragma unroll
      for (int s = 0; s < 8; ++s)
        #pragma unroll
        for (int j2 = 0; j2 < 4; ++j2){
          if (ph == 0) red[s*256 + dd + j2]  = upd[s][j2];
          else         red[s*256 + dd + j2] += upd[s][j2];
        }
    }
    __syncthreads();
  }
  {
    float* up = upd_part + (size_t)bid * 2048;
    #pragma unroll
    for (int i = 0; i < 8; ++i) up[i*256 + tid] = red[i*256 + tid];
  }
  {
    int col = lane & 15, g = lane >> 4;
    #pragma unroll
    for (int dsh = 1; dsh < 16; dsh <<= 1){
      sp[0] += __shfl_xor(sp[0], dsh, 64); sp[1] += __shfl_xor(sp[1], dsh, 64);
      sp[2] += __shfl_xor(sp[2], dsh, 64); sp[3] += __shfl_xor(sp[3], dsh, 64);
    }
    if (col == 0 && g < 2){
      atomicAdd(&ssum[g*4 + 0], sp[0]);
      atomicAdd(&ssum[g*4 + 1], sp[1]);
      atomicAdd(&ssum[g*4 + 2], sp[2]);
      atomicAdd(&ssum[g*4 + 3], sp[3]);
    }
    __syncthreads();
    if (tid < 8) sum_part[(size_t)bid*8 + tid] = ssum[tid];
  }
}

extern "C" void kernel_launch(void* const* d_in, const int* in_sizes, int n_in,
                              void* d_out, int out_size, void* d_ws, size_t ws_size,
                              hipStream_t stream){
  const float* inputs = (const float*)d_in[0];
  const float* mu     = (const float*)d_in[1];
  const float* lsig   = (const float*)d_in[2];
  const float* noise  = (const float*)d_in[3];
  const float* Wq     = (const float*)d_in[4];
  const float* Wk     = (const float*)d_in[5];
  const float* Wv     = (const float*)d_in[6];
  const float* ng     = (const float*)d_in[7];
  const float* nb     = (const float*)d_in[8];
  const float* wih    = (const float*)d_in[9];
  const float* whh    = (const float*)d_in[10];
  const float* bih    = (const float*)d_in[11];
  const float* bhh    = (const float*)d_in[12];
  const float* mng    = (const float*)d_in[13];
  const float* mnb    = (const float*)d_in[14];
  const float* w1     = (const float*)d_in[15];
  const float* b1     = (const float*)d_in[16];
  const float* w2     = (const float*)d_in[17];
  const float* b2     = (const float*)d_in[18];
  float* slots = (float*)d_out;

  char* ws = (char*)d_ws;
  uint16_t* Wt       = (uint16_t*)(ws + 0);            // 256 KB
  uint16_t* qbf      = (uint16_t*)(ws + 0x40000);      // 128 KB
  float*    sum_part = (float*)   (ws + 0x60000);      // 16 KB
  float*    upd_part = (float*)   (ws + 0x64000);      // 4 MB
  uint16_t* Wqt      = (uint16_t*)(ws + 0x480000);     // 128 KB
  uint16_t* Bcat     = (uint16_t*)(ws + 0x4A0000);     // 1 MB
  uint16_t* w1t      = (uint16_t*)(ws + 0x5A0000);     // 512 KB
  uint16_t* w2t      = (uint16_t*)(ws + 0x620000);     // 512 KB
  float*    bc       = (float*)   (ws + 0x6A0000);     // 4 KB
  uint16_t* Acat     = (uint16_t*)(ws + 0x6B0000);     // 256 KB
  float*    G        = (float*)   (ws + 0x6F0000);     // 1 MB
  uint16_t* snb      = (uint16_t*)(ws + 0x7F0000);     // 128 KB
  float*    s2f      = (float*)   (ws + 0x810000);     // 256 KB
  uint16_t* Kp       = (uint16_t*)(ws + 0x1000000);    // 64 MB
  uint16_t* Vp       = (uint16_t*)(ws + 0x5000000);    // 64 MB (ends 144 MB)

  hipLaunchKernelGGL(k_prep, dim3(3329), dim3(256), 0, stream,
                     Wk, Wv, Wq, wih, whh, bih, bhh, w1, w2, mu, lsig, noise,
                     Wt, Wqt, Bcat, bc, w1t, w2t, slots);
  hipLaunchKernelGGL(k_proj, dim3(4096), dim3(256), 0, stream, inputs, Wt, Kp, Vp);

  for (int it = 0; it < ITERS_; ++it){
    hipLaunchKernelGGL(k_qln,     dim3(16),   dim3(256), 0, stream, slots, Wqt, ng, nb, qbf);
    hipLaunchKernelGGL(k_attn,    dim3(512),  dim3(256), 0, stream, qbf, Kp, Vp, upd_part, sum_part);
    hipLaunchKernelGGL(k_gru_pre, dim3(256),  dim3(256), 0, stream, upd_part, sum_part, slots, Acat);
    hipLaunchKernelGGL(k_gemmG,   dim3(16,4), dim3(256), 0, stream, Acat, Bcat, G);
    hipLaunchKernelGGL(k_combine, dim3(256),  dim3(256), 0, stream, G, bc, slots, mng, mnb, s2f, snb);
    hipLaunchKernelGGL(k_mlp,     dim3(16),   dim3(256), 0, stream, snb, w1t, b1, w2t, b2, s2f, slots);
  }
}

// Round 5
// 516.215 us; speedup vs baseline: 1.2498x; 1.2498x over previous
//
#include <hip/hip_runtime.h>
#include <stdint.h>

#define B_ 32
#define T_ 4096
#define D_ 256
#define S_ 8
#define ITERS_ 3
#define SCALE_ 0.0625f   // 256^-0.5
#define EPS_ 1e-8f
#define NCH 16
#define CHUNK (T_/NCH)   // 256

typedef short short8 __attribute__((ext_vector_type(8)));
typedef float f32x4 __attribute__((ext_vector_type(4)));

__device__ __forceinline__ uint32_t f2bf1(float x){
  union { float f; uint32_t u; } c; c.f = x;
  return (c.u + 0x7fffu + ((c.u >> 16) & 1u)) >> 16;
}
__device__ __forceinline__ uint32_t pack2bf(float a, float b){
  return f2bf1(a) | (f2bf1(b) << 16);
}
__device__ __forceinline__ uint32_t cvtpk2bf(float a, float b){
  uint32_t r;
  asm("v_cvt_pk_bf16_f32 %0, %1, %2" : "=v"(r) : "v"(a), "v"(b));
  return r;
}
__device__ __forceinline__ float bflo(uint32_t u){ union{uint32_t u;float f;} c; c.u = u << 16; return c.f; }
__device__ __forceinline__ float bfhi(uint32_t u){ union{uint32_t u;float f;} c; c.u = u & 0xffff0000u; return c.f; }

__device__ __forceinline__ void gload16(const uint16_t* g, uint16_t* l){
  __builtin_amdgcn_global_load_lds(
      (const __attribute__((address_space(1))) uint32_t*)g,
      (__attribute__((address_space(3))) uint32_t*)l, 16, 0, 0);
}

// ---------------- mega prep: weight transforms + slot init, one launch ----------------
__global__ __launch_bounds__(256) void k_prep(const float* __restrict__ Wk, const float* __restrict__ Wv,
                                              const float* __restrict__ Wq,
                                              const float* __restrict__ wih, const float* __restrict__ whh,
                                              const float* __restrict__ bih, const float* __restrict__ bhh,
                                              const float* __restrict__ w1, const float* __restrict__ w2,
                                              const float* __restrict__ mu, const float* __restrict__ ls,
                                              const float* __restrict__ noise,
                                              uint16_t* __restrict__ Wt, uint16_t* __restrict__ Wqt,
                                              uint16_t* __restrict__ Bcat, float* __restrict__ bc,
                                              uint16_t* __restrict__ w1t, uint16_t* __restrict__ w2t,
                                              float* __restrict__ slots){
  int g = blockIdx.x, tid = threadIdx.x;
  if (g < 512){
    int n = g, k = tid;
    float v = (n < 256) ? Wk[k*256 + n] : Wv[k*256 + (n - 256)];
    Wt[n*256 + k] = (uint16_t)f2bf1(v);
  } else if (g < 768){
    int n = g - 512, k = tid;
    Wqt[n*256 + k] = (uint16_t)f2bf1(Wq[k*256 + n] * SCALE_);
  } else if (g < 1792){
    int n = g - 768;
    #pragma unroll
    for (int j = 0; j < 2; ++j){
      int k = j*256 + tid;
      float v;
      if (n < 768) v = (k < 256) ? wih[k*768 + n] : whh[(k-256)*768 + n];
      else         v = (k < 256) ? 0.f            : whh[(k-256)*768 + 512 + (n-768)];
      Bcat[(size_t)n*512 + k] = (uint16_t)f2bf1(v);
    }
  } else if (g < 1793){
    #pragma unroll
    for (int j = 0; j < 4; ++j){
      int i = j*256 + tid;
      float v;
      if (i < 512) v = bih[i] + bhh[i];
      else if (i < 768) v = bih[i];
      else v = bhh[i - 256];
      bc[i] = v;
    }
  } else if (g < 2817){
    int n = g - 1793, k = tid;
    w1t[(size_t)n*256 + k] = (uint16_t)f2bf1(w1[(size_t)k*1024 + n]);
  } else if (g < 3073){
    int n = g - 2817;
    #pragma unroll
    for (int j = 0; j < 4; ++j){
      int k = j*256 + tid;
      w2t[(size_t)n*1024 + k] = (uint16_t)f2bf1(w2[(size_t)k*256 + n]);
    }
  } else {
    int i = (g - 3073)*256 + tid;
    int d = i & 255;
    slots[i] = mu[d] + __expf(ls[d]) * noise[i];
  }
}

// ---------------- projection GEMM: [131072,256]x[256,512] -> K,V bf16 ----------------
// BK=64, fragment-major LDS (zero-conflict ds_read_b128), B via global_load_lds.
__global__ __launch_bounds__(256) void k_proj(const float* __restrict__ X,
                                              const uint16_t* __restrict__ Wt,
                                              uint16_t* __restrict__ Kp,
                                              uint16_t* __restrict__ Vp){
  __shared__ __align__(16) uint16_t As[8192];   // 16 frag-blocks x 512 u16 (1KB)
  __shared__ __align__(16) uint16_t Bs[8192];
  __shared__ __align__(16) uint16_t Cs[64*136]; // half-tile epilogue, padded pitch
  int bid = blockIdx.x;
  int x = bid & 7, j = bid >> 3;
  int tau = 512*x + j;              // groups of 4 consecutive tau share A-panel, same XCD
  int m0 = (tau >> 2) * 128;
  int n0 = (tau & 3) * 128;
  int tid = threadIdx.x;
  int lane = tid & 63, wid = tid >> 6;
  int wm = wid >> 1, wn = wid & 1;
  int rsel = lane & 15, g = lane >> 4;

  f32x4 acc[4][4];
  #pragma unroll
  for (int a = 0; a < 4; ++a)
    #pragma unroll
    for (int b = 0; b < 4; ++b)
      acc[a][b] = (f32x4){0.f,0.f,0.f,0.f};

  for (int ks = 0; ks < 4; ++ks){
    int k0 = ks*64;
    // B: 4 gload_lds chunks per wave; frag-major content via per-lane global src
    #pragma unroll
    for (int i = 0; i < 4; ++i){
      int c = wid*4 + i;            // 0..15: frag-block (T=c>>1, kk=c&1)
      int T = c >> 1, kk = c & 1;
      const uint16_t* src = Wt + (size_t)(n0 + T*16 + rsel)*256 + k0 + kk*32 + g*8;
      gload16(src, &Bs[c*512]);
    }
    // A: reg-staged fp32->bf16, frag-major dest (consecutive-lane writes)
    #pragma unroll
    for (int i2 = 0; i2 < 4; ++i2){
      int chunk = i2*256 + tid;     // 0..1023 (16 blocks x 64 lanes)
      int blk = chunk >> 6, fl = chunk & 63;
      int T = blk >> 1, kk = blk & 1;
      const float* gp = X + (size_t)(m0 + T*16 + (fl & 15))*256 + k0 + kk*32 + (fl >> 4)*8;
      float4 a = *(const float4*)gp;
      float4 b = *(const float4*)(gp + 4);
      uint4 w;
      w.x = cvtpk2bf(a.x, a.y); w.y = cvtpk2bf(a.z, a.w);
      w.z = cvtpk2bf(b.x, b.y); w.w = cvtpk2bf(b.z, b.w);
      *(uint4*)&As[chunk*8] = w;
    }
    __syncthreads();
    #pragma unroll
    for (int kk = 0; kk < 2; ++kk){
      short8 af[4], bfv[4];
      #pragma unroll
      for (int t = 0; t < 4; ++t)
        af[t] = *(const short8*)&As[(((wm*4 + t) << 1) | kk)*512 + lane*8];
      #pragma unroll
      for (int t = 0; t < 4; ++t)
        bfv[t] = *(const short8*)&Bs[(((wn*4 + t) << 1) | kk)*512 + lane*8];
      #pragma unroll
      for (int a = 0; a < 4; ++a)
        #pragma unroll
        for (int b = 0; b < 4; ++b)
          acc[a][b] = __builtin_amdgcn_mfma_f32_16x16x32_bf16(af[a], bfv[b], acc[a][b], 0, 0, 0);
    }
    __syncthreads();
  }
  // epilogue: two 64-row halves through Cs
  uint16_t* outp = (n0 < 256) ? Kp : Vp;
  int nbase = n0 & 255;
  for (int h = 0; h < 2; ++h){
    if (wm == h){
      #pragma unroll
      for (int a = 0; a < 4; ++a)
        #pragma unroll
        for (int b = 0; b < 4; ++b)
          #pragma unroll
          for (int r = 0; r < 4; ++r)
            Cs[(a*16 + g*4 + r)*136 + wn*64 + b*16 + rsel] = (uint16_t)f2bf1(acc[a][b][r]);
    }
    __syncthreads();
    #pragma unroll
    for (int i = 0; i < 2; ++i){
      int task = i*256 + tid;       // 512: 64 rows x 8 segs of 16 u16
      int row = task >> 3, seg = task & 7;
      uint4 v = *(uint4*)&Cs[row*136 + seg*16];
      *(uint4*)&outp[(size_t)(m0 + h*64 + row)*256 + nbase + seg*16] = v;
    }
    if (h == 0) __syncthreads();
  }
}

// ---------------- generic small GEMM (64x64 tiles, optional split-K via gridDim.z) ----
// MODE 0: Cf = acc (fp32 store, gridz must be 1)
// MODE 1: Cb = bf16(relu(acc+bias[n]))
// MODE 4: atomicAdd(Cf, acc)
#define GPIT 40
template<int MODE>
__global__ __launch_bounds__(256) void k_gemm64(const uint16_t* __restrict__ A,
                                                const uint16_t* __restrict__ Bm,
                                                const float* __restrict__ bias,
                                                float* __restrict__ Cf,
                                                uint16_t* __restrict__ Cb,
                                                int N, int K, int kpb){
  __shared__ __align__(16) uint16_t As[64*GPIT];
  __shared__ __align__(16) uint16_t Bs[64*GPIT];
  int m0 = blockIdx.y * 64, n0 = blockIdx.x * 64;
  int kb = blockIdx.z * kpb;
  int tid = threadIdx.x, lane = tid & 63, wid = tid >> 6;
  int wm = wid >> 1, wn = wid & 1;
  int rsel = lane & 15, g = lane >> 4;
  f32x4 acc[2][2];
  #pragma unroll
  for (int a = 0; a < 2; ++a)
    #pragma unroll
    for (int b = 0; b < 2; ++b)
      acc[a][b] = (f32x4){0.f,0.f,0.f,0.f};
  int row_s = tid >> 2, seg = tid & 3;
  for (int k0 = kb; k0 < kb + kpb; k0 += 32){
    *(uint4*)&As[row_s*GPIT + seg*8] = *(const uint4*)(A  + (size_t)(m0+row_s)*K + k0 + seg*8);
    *(uint4*)&Bs[row_s*GPIT + seg*8] = *(const uint4*)(Bm + (size_t)(n0+row_s)*K + k0 + seg*8);
    __syncthreads();
    short8 af[2], bfr[2];
    #pragma unroll
    for (int t = 0; t < 2; ++t)
      af[t]  = *(const short8*)&As[(wm*32 + t*16 + rsel)*GPIT + g*8];
    #pragma unroll
    for (int t = 0; t < 2; ++t)
      bfr[t] = *(const short8*)&Bs[(wn*32 + t*16 + rsel)*GPIT + g*8];
    #pragma unroll
    for (int a = 0; a < 2; ++a)
      #pragma unroll
      for (int b = 0; b < 2; ++b)
        acc[a][b] = __builtin_amdgcn_mfma_f32_16x16x32_bf16(af[a], bfr[b], acc[a][b], 0, 0, 0);
    __syncthreads();
  }
  #pragma unroll
  for (int a = 0; a < 2; ++a)
    #pragma unroll
    for (int b = 0; b < 2; ++b)
      #pragma unroll
      for (int r = 0; r < 4; ++r){
        int mrow = m0 + wm*32 + a*16 + g*4 + r;
        int ncol = n0 + wn*32 + b*16 + rsel;
        float v = acc[a][b][r];
        if (MODE == 0) Cf[(size_t)mrow*N + ncol] = v;
        if (MODE == 1) Cb[(size_t)mrow*N + ncol] = (uint16_t)f2bf1(fmaxf(v + bias[ncol], 0.f));
        if (MODE == 4) atomicAdd(&Cf[(size_t)mrow*N + ncol], v);
      }
}

// ---------------- reduce attn partials -> Acat bf16 [256][512] = [u | h] ----------------
__global__ __launch_bounds__(256) void k_gru_pre(const float* __restrict__ upd_part,
                                                 const float* __restrict__ sum_part,
                                                 const float* __restrict__ slots,
                                                 uint16_t* __restrict__ Acat){
  int row = blockIdx.x;
  int b = row >> 3, s = row & 7;
  int d = threadIdx.x;
  float sum = 0.f;
  #pragma unroll
  for (int ch = 0; ch < 16; ++ch) sum += sum_part[(size_t)(b*16 + ch)*8 + s];
  float acc = 0.f;
  #pragma unroll
  for (int ch = 0; ch < 16; ++ch) acc += upd_part[(size_t)(b*16 + ch)*2048 + s*256 + d];
  Acat[(size_t)row*512 + d]       = (uint16_t)f2bf1(acc / sum);
  Acat[(size_t)row*512 + 256 + d] = (uint16_t)f2bf1(slots[row*256 + d]);
}

// ---------------- GRU combine + LN; slots = s2 + b2 (residual base for mlp2 atomics) ----
__global__ __launch_bounds__(256) void k_combine(const float* __restrict__ G,
                                                 const float* __restrict__ bc,
                                                 float* __restrict__ slots,
                                                 const float* __restrict__ mng,
                                                 const float* __restrict__ mnb,
                                                 const float* __restrict__ b2,
                                                 uint16_t* __restrict__ snb){
  __shared__ float red[8];
  int row = blockIdx.x, c = threadIdx.x;
  int lane = c & 63, wid = c >> 6;
  const float* Gr = G + (size_t)row*1024;
  float r  = 1.f / (1.f + __expf(-(Gr[c]       + bc[c])));
  float z  = 1.f / (1.f + __expf(-(Gr[256 + c] + bc[256 + c])));
  float Gn = Gr[512 + c], Gh = Gr[768 + c];
  float nn = tanhf((Gn - Gh + bc[512 + c]) + r*(Gh + bc[768 + c]));
  float hv = slots[row*256 + c];
  float s2 = (1.f - z)*nn + z*hv;
  float p1 = s2, p2 = s2*s2;
  #pragma unroll
  for (int d = 32; d; d >>= 1){ p1 += __shfl_down(p1, d, 64); p2 += __shfl_down(p2, d, 64); }
  if (lane == 0){ red[wid] = p1; red[4 + wid] = p2; }
  __syncthreads();
  float mu = (red[0]+red[1]+red[2]+red[3]) * (1.f/256.f);
  float ms = (red[4]+red[5]+red[6]+red[7]) * (1.f/256.f);
  float rstd = rsqrtf(ms - mu*mu + 1e-5f);
  snb[row*256 + c] = (uint16_t)f2bf1((s2 - mu)*rstd*mng[c] + mnb[c]);
  slots[row*256 + c] = s2 + b2[c];
}

// ---------------- per-iter: fused LN+qGEMM + dots->softmax(S)->unnorm PV ----------------
__global__ __launch_bounds__(256) void k_attn(const float* __restrict__ slots,
                                              const uint16_t* __restrict__ Wqt,
                                              const float* __restrict__ ng,
                                              const float* __restrict__ nb,
                                              const uint16_t* __restrict__ Kp,
                                              const uint16_t* __restrict__ Vp,
                                              float* __restrict__ upd_part,
                                              float* __restrict__ sum_part){
  __shared__ __align__(16) uint16_t qs[16*264];
  __shared__ __align__(16) uint16_t Ks[64*264];
  __shared__ __align__(16) uint32_t attp[64*4];
  __shared__ union { uint16_t snl[16*264]; float red[8*256]; } u_;
  __shared__ float ssum[8];
  int bid = blockIdx.x;
  int b = bid >> 4, ch = bid & 15;
  int tid = threadIdx.x, lane = tid & 63, wid = tid >> 6;
  int rsel = lane & 15, g = lane >> 4;
  // ---- phase 0: LN(slots rows b*8..b*8+7) -> snl (rows 8..15 zeroed)
  {
    int r = tid >> 5, h32 = tid & 31;       // 8 rows x 32 threads, 8 elems each
    const float* sp = slots + (size_t)(b*8 + r)*256 + h32*8;
    float4 v0 = *(const float4*)sp, v1 = *(const float4*)(sp + 4);
    float xv[8] = {v0.x,v0.y,v0.z,v0.w,v1.x,v1.y,v1.z,v1.w};
    float s1 = 0.f, s2 = 0.f;
    #pragma unroll
    for (int i = 0; i < 8; ++i){ s1 += xv[i]; s2 += xv[i]*xv[i]; }
    #pragma unroll
    for (int m = 1; m < 32; m <<= 1){ s1 += __shfl_xor(s1, m, 64); s2 += __shfl_xor(s2, m, 64); }
    float mu = s1 * (1.f/256.f);
    float ms = s2 * (1.f/256.f);
    float rstd = rsqrtf(ms - mu*mu + 1e-5f);
    const float* ngp = ng + h32*8; const float* nbp = nb + h32*8;
    uint32_t pk[4];
    #pragma unroll
    for (int i = 0; i < 4; ++i){
      float a = (xv[2*i]   - mu)*rstd*ngp[2*i]   + nbp[2*i];
      float bb = (xv[2*i+1] - mu)*rstd*ngp[2*i+1] + nbp[2*i+1];
      pk[i] = pack2bf(a, bb);
    }
    *(uint4*)&u_.snl[r*264 + h32*8] = (uint4){pk[0],pk[1],pk[2],pk[3]};
    uint32_t* qd = (uint32_t*)u_.snl;
    #pragma unroll
    for (int i = 0; i < 5; ++i){
      int idx = i*256 + tid;
      if (idx < 1056) qd[1056 + idx] = 0u;   // rows 8..15 (dword 8*132=1056)
    }
    if (tid < 8) ssum[tid] = 0.f;
  }
  __syncthreads();
  // ---- phase 1: q = snl @ Wqt^T (scale folded), write bf16 to qs
  {
    short8 aqs[8];
    #pragma unroll
    for (int kk = 0; kk < 8; ++kk)
      aqs[kk] = *(const short8*)((const char*)u_.snl + rsel*528 + kk*64 + g*16);
    int n0w = wid*64;
    #pragma unroll
    for (int nt = 0; nt < 4; ++nt){
      f32x4 acc = (f32x4){0.f,0.f,0.f,0.f};
      #pragma unroll
      for (int kk = 0; kk < 8; ++kk){
        short8 bfr = *(const short8*)&Wqt[(size_t)(n0w + nt*16 + rsel)*256 + kk*32 + g*8];
        acc = __builtin_amdgcn_mfma_f32_16x16x32_bf16(aqs[kk], bfr, acc, 0, 0, 0);
      }
      #pragma unroll
      for (int r4 = 0; r4 < 4; ++r4)
        qs[(g*4 + r4)*264 + n0w + nt*16 + rsel] = (uint16_t)f2bf1(acc[r4]);
    }
  }
  __syncthreads();
  // ---- phase 2: aq frags, then K/V loop
  short8 aq[8];
  {
    const char* qb = (const char*)qs;
    #pragma unroll
    for (int kk = 0; kk < 8; ++kk)
      aq[kk] = *(const short8*)(qb + rsel*528 + kk*64 + g*16);
  }
  float upd[8][4];
  #pragma unroll
  for (int s = 0; s < 8; ++s){ upd[s][0]=0.f; upd[s][1]=0.f; upd[s][2]=0.f; upd[s][3]=0.f; }
  float sp[4] = {0.f,0.f,0.f,0.f};
  int dd = lane * 4;
  int tq = wid;

  for (int st = 0; st < 4; ++st){
    int t0 = ch*CHUNK + st*64;
    {
      const char* kg = (const char*)Kp + ((size_t)(b*T_ + t0) << 9);
      char* kd = (char*)Ks;
      #pragma unroll
      for (int i = 0; i < 8; ++i){
        int task = i*256 + tid;
        int row = task >> 5, seg = task & 31;
        uint4 v = *(const uint4*)(kg + (row << 9) + (seg << 4));
        *(uint4*)(kd + row*528 + seg*16) = v;
      }
    }
    __syncthreads();
    f32x4 dot = (f32x4){0.f,0.f,0.f,0.f};
    {
      const char* kb = (const char*)Ks + (wid*16 + rsel)*528 + g*16;
      #pragma unroll
      for (int kk = 0; kk < 8; ++kk){
        short8 bf = *(const short8*)(kb + kk*64);
        dot = __builtin_amdgcn_mfma_f32_16x16x32_bf16(aq[kk], bf, dot, 0, 0, 0);
      }
    }
    float x0 = dot[0], x1 = dot[1], x2 = dot[2], x3 = dot[3];
    float y0 = __shfl_xor(x0, 16, 64), y1 = __shfl_xor(x1, 16, 64);
    float y2 = __shfl_xor(x2, 16, 64), y3 = __shfl_xor(x3, 16, 64);
    float m = fmaxf(fmaxf(fmaxf(x0,x1), fmaxf(x2,x3)), fmaxf(fmaxf(y0,y1), fmaxf(y2,y3)));
    float e0 = __expf(x0-m), e1 = __expf(x1-m), e2 = __expf(x2-m), e3 = __expf(x3-m);
    float f0 = __expf(y0-m), f1 = __expf(y1-m), f2 = __expf(y2-m), f3 = __expf(y3-m);
    float inv = 1.f / (e0+e1+e2+e3+f0+f1+f2+f3);
    float p0 = e0*inv + EPS_, p1 = e1*inv + EPS_, p2 = e2*inv + EPS_, p3 = e3*inv + EPS_;
    if (g < 2){
      sp[0] += p0; sp[1] += p1; sp[2] += p2; sp[3] += p3;
      int t = wid*16 + rsel;
      attp[t*4 + g*2 + 0] = pack2bf(p0, p1);
      attp[t*4 + g*2 + 1] = pack2bf(p2, p3);
    }
    __syncthreads();
    {
      const char* vg = (const char*)Vp + ((size_t)(b*T_ + t0) << 9) + (size_t)dd*2;
      #pragma unroll
      for (int tt = 0; tt < 16; ++tt){
        int tl = tq*16 + tt;
        uint2 vv = *(const uint2*)(vg + ((size_t)tl << 9));
        uint4 aa = *(const uint4*)&attp[tl*4];
        float v0 = bflo(vv.x), v1 = bfhi(vv.x), v2 = bflo(vv.y), v3 = bfhi(vv.y);
        float av[8];
        av[0] = bflo(aa.x); av[1] = bfhi(aa.x); av[2] = bflo(aa.y); av[3] = bfhi(aa.y);
        av[4] = bflo(aa.z); av[5] = bfhi(aa.z); av[6] = bflo(aa.w); av[7] = bfhi(aa.w);
        #pragma unroll
        for (int s = 0; s < 8; ++s){
          upd[s][0] = fmaf(av[s], v0, upd[s][0]);
          upd[s][1] = fmaf(av[s], v1, upd[s][1]);
          upd[s][2] = fmaf(av[s], v2, upd[s][2]);
          upd[s][3] = fmaf(av[s], v3, upd[s][3]);
        }
      }
    }
    __syncthreads();
  }
  for (int ph = 0; ph < 4; ++ph){
    if (tq == ph){
      #pragma unroll
      for (int s = 0; s < 8; ++s)
        #pragma unroll
        for (int j2 = 0; j2 < 4; ++j2){
          if (ph == 0) u_.red[s*256 + dd + j2]  = upd[s][j2];
          else         u_.red[s*256 + dd + j2] += upd[s][j2];
        }
    }
    __syncthreads();
  }
  {
    float* up = upd_part + (size_t)bid * 2048;
    #pragma unroll
    for (int i = 0; i < 8; ++i) up[i*256 + tid] = u_.red[i*256 + tid];
  }
  {
    #pragma unroll
    for (int dsh = 1; dsh < 16; dsh <<= 1){
      sp[0] += __shfl_xor(sp[0], dsh, 64); sp[1] += __shfl_xor(sp[1], dsh, 64);
      sp[2] += __shfl_xor(sp[2], dsh, 64); sp[3] += __shfl_xor(sp[3], dsh, 64);
    }
    if (rsel == 0 && g < 2){
      atomicAdd(&ssum[g*4 + 0], sp[0]);
      atomicAdd(&ssum[g*4 + 1], sp[1]);
      atomicAdd(&ssum[g*4 + 2], sp[2]);
      atomicAdd(&ssum[g*4 + 3], sp[3]);
    }
    __syncthreads();
    if (tid < 8) sum_part[(size_t)bid*8 + tid] = ssum[tid];
  }
}

extern "C" void kernel_launch(void* const* d_in, const int* in_sizes, int n_in,
                              void* d_out, int out_size, void* d_ws, size_t ws_size,
                              hipStream_t stream){
  const float* inputs = (const float*)d_in[0];
  const float* mu     = (const float*)d_in[1];
  const float* lsig   = (const float*)d_in[2];
  const float* noise  = (const float*)d_in[3];
  const float* Wq     = (const float*)d_in[4];
  const float* Wk     = (const float*)d_in[5];
  const float* Wv     = (const float*)d_in[6];
  const float* ng     = (const float*)d_in[7];
  const float* nb     = (const float*)d_in[8];
  const float* wih    = (const float*)d_in[9];
  const float* whh    = (const float*)d_in[10];
  const float* bih    = (const float*)d_in[11];
  const float* bhh    = (const float*)d_in[12];
  const float* mng    = (const float*)d_in[13];
  const float* mnb    = (const float*)d_in[14];
  const float* w1     = (const float*)d_in[15];
  const float* b1     = (const float*)d_in[16];
  const float* w2     = (const float*)d_in[17];
  const float* b2     = (const float*)d_in[18];
  float* slots = (float*)d_out;

  char* ws = (char*)d_ws;
  uint16_t* Wt       = (uint16_t*)(ws + 0);            // 256 KB
  float*    sum_part = (float*)   (ws + 0x60000);      // 16 KB
  float*    upd_part = (float*)   (ws + 0x64000);      // 4 MB
  uint16_t* Wqt      = (uint16_t*)(ws + 0x480000);     // 128 KB
  uint16_t* Bcat     = (uint16_t*)(ws + 0x4A0000);     // 1 MB
  uint16_t* w1t      = (uint16_t*)(ws + 0x5A0000);     // 512 KB
  uint16_t* w2t      = (uint16_t*)(ws + 0x620000);     // 512 KB
  float*    bc       = (float*)   (ws + 0x6A0000);     // 4 KB
  uint16_t* Acat     = (uint16_t*)(ws + 0x6B0000);     // 256 KB
  float*    G        = (float*)   (ws + 0x6F0000);     // 1 MB
  uint16_t* snb      = (uint16_t*)(ws + 0x7F0000);     // 128 KB
  uint16_t* h1b      = (uint16_t*)(ws + 0x850000);     // 512 KB
  uint16_t* Kp       = (uint16_t*)(ws + 0x1000000);    // 64 MB
  uint16_t* Vp       = (uint16_t*)(ws + 0x5000000);    // 64 MB

  hipLaunchKernelGGL(k_prep, dim3(3329), dim3(256), 0, stream,
                     Wk, Wv, Wq, wih, whh, bih, bhh, w1, w2, mu, lsig, noise,
                     Wt, Wqt, Bcat, bc, w1t, w2t, slots);
  hipLaunchKernelGGL(k_proj, dim3(4096), dim3(256), 0, stream, inputs, Wt, Kp, Vp);

  for (int it = 0; it < ITERS_; ++it){
    hipLaunchKernelGGL(k_attn,      dim3(512),    dim3(256), 0, stream,
                       slots, Wqt, ng, nb, Kp, Vp, upd_part, sum_part);
    hipLaunchKernelGGL(k_gru_pre,   dim3(256),    dim3(256), 0, stream,
                       upd_part, sum_part, slots, Acat);
    hipLaunchKernelGGL(k_gemm64<0>, dim3(16,4,1), dim3(256), 0, stream,
                       Acat, Bcat, (const float*)nullptr, G, (uint16_t*)nullptr, 1024, 512, 512);
    hipLaunchKernelGGL(k_combine,   dim3(256),    dim3(256), 0, stream,
                       G, bc, slots, mng, mnb, b2, snb);
    hipLaunchKernelGGL(k_gemm64<1>, dim3(16,4,1), dim3(256), 0, stream,
                       snb, w1t, b1, (float*)nullptr, h1b, 1024, 256, 256);
    hipLaunchKernelGGL(k_gemm64<4>, dim3(4,4,4),  dim3(256), 0, stream,
                       h1b, w2t, (const float*)nullptr, slots, (uint16_t*)nullptr, 256, 1024, 256);
  }
}